// Round 5
// baseline (1143.169 us; speedup 1.0000x reference)
//
#include <hip/hip_runtime.h>
#include <hip/hip_bf16.h>

#define HH 256
#define WW2 256
#define NB 2
#define DIM 192
#define HEADS 4
#define CP 48
#define WS 8
#define HN 32
#define WN 32
#define HW (HH*WW2)
#define C3 (3*DIM)

// ---------------------------------------------------------------------------
// 1x1 conv as GEMM: Y[b,o,hw] = sum_c Wm[o,c] * X[b,(c),hw]
// Runtime batch count (nbat) + X/Y batch strides so the same kernel serves
// the full-batch path and the per-batch low-workspace fallback.
// tile: 64 (o) x 128 (hw), K-chunk 32, microtile 4x8 per thread, 256 threads
// ---------------------------------------------------------------------------
template<int COUT>
__global__ __launch_bounds__(256)
void conv1x1_kernel(const float* __restrict__ Wm, const float* __restrict__ X,
                    float* __restrict__ Y, size_t xbstride, size_t ybstride,
                    int nbat) {
  constexpr int OT = COUT / 64;
  constexpr int NT = HW / 128;          // 512 -> total always divisible by 8
  const int TOTAL = nbat * NT * OT;
  int gid = blockIdx.x;
  int sw = (gid & 7) * (TOTAL >> 3) + (gid >> 3);   // XCD-chunked swizzle
  int o_t = sw % OT;
  int rem = sw / OT;
  int b   = rem % nbat;
  int n_t = rem / nbat;

  const int o0 = o_t * 64;
  const int n0 = n_t * 128;
  const float* Xb = X + (size_t)b * xbstride;
  float* Yb = Y + (size_t)b * ybstride;

  __shared__ __align__(16) float Ws[32][68];    // [kk][o]  transposed, padded
  __shared__ __align__(16) float Xs[32][132];   // [kk][n]  padded

  const int tid = threadIdx.x;
  const int tx = tid & 15;
  const int ty = tid >> 4;

  float acc[4][8];
#pragma unroll
  for (int i = 0; i < 4; ++i)
#pragma unroll
    for (int j = 0; j < 8; ++j) acc[i][j] = 0.f;

  for (int k0 = 0; k0 < DIM; k0 += 32) {
    {
      int kk = tid & 31, r8 = tid >> 5;  // r8 in 0..7
      const float* wp = Wm + (size_t)(o0 + r8 * 8) * DIM + k0 + kk;
#pragma unroll
      for (int j = 0; j < 8; ++j)
        Ws[kk][r8 * 8 + j] = wp[(size_t)j * DIM];
    }
    {
      int kk = tid >> 3, x0 = (tid & 7) * 16;
      const float* xp = Xb + (size_t)(k0 + kk) * HW + n0 + x0;
      float4 v0 = *(const float4*)(xp);
      float4 v1 = *(const float4*)(xp + 4);
      float4 v2 = *(const float4*)(xp + 8);
      float4 v3 = *(const float4*)(xp + 12);
      *(float4*)&Xs[kk][x0]      = v0;
      *(float4*)&Xs[kk][x0 + 4]  = v1;
      *(float4*)&Xs[kk][x0 + 8]  = v2;
      *(float4*)&Xs[kk][x0 + 12] = v3;
    }
    __syncthreads();
#pragma unroll
    for (int kk = 0; kk < 32; ++kk) {
      float4 a  = *(const float4*)&Ws[kk][ty * 4];
      float4 b0 = *(const float4*)&Xs[kk][tx * 4];
      float4 b1 = *(const float4*)&Xs[kk][64 + tx * 4];
      float av[4] = {a.x, a.y, a.z, a.w};
      float bv[8] = {b0.x, b0.y, b0.z, b0.w, b1.x, b1.y, b1.z, b1.w};
#pragma unroll
      for (int i = 0; i < 4; ++i)
#pragma unroll
        for (int j = 0; j < 8; ++j)
          acc[i][j] = fmaf(av[i], bv[j], acc[i][j]);
    }
    __syncthreads();
  }

#pragma unroll
  for (int i = 0; i < 4; ++i) {
    float* yp = Yb + (size_t)(o0 + ty * 4 + i) * HW + n0;
    float4 s0 = {acc[i][0], acc[i][1], acc[i][2], acc[i][3]};
    float4 s1 = {acc[i][4], acc[i][5], acc[i][6], acc[i][7]};
    *(float4*)(yp + tx * 4)      = s0;
    *(float4*)(yp + 64 + tx * 4) = s1;
  }
}

// ---------------------------------------------------------------------------
// depthwise 3x3, SAME padding, one 192-channel chunk.
// src: [b][192][HW] (b-stride DIM*HW); dst: [b][C3][HW] layout at chunk offset
// (b-stride C3*HW). Launch with gridDim.z = nbat*DIM; single-batch callers
// pass pre-offset pointers and gridDim.z = DIM (b evaluates to 0).
// ---------------------------------------------------------------------------
__global__ __launch_bounds__(256)
void dwconv_kernel(const float* __restrict__ Wd, const float* __restrict__ X,
                   float* __restrict__ Y) {
  const int bc = blockIdx.z;          // b*DIM + ch
  const int ch = bc % DIM;
  const int b  = bc / DIM;
  const int y0 = blockIdx.y * 16;
  const int x0 = blockIdx.x * 64;
  const float* Xc = X + (size_t)bc * HW;
  float* Yc = Y + ((size_t)b * C3 + ch) * HW;

  float w[9];
#pragma unroll
  for (int i = 0; i < 9; ++i) w[i] = Wd[ch * 9 + i];

  __shared__ __align__(16) float tile[18][66];
  const int tid = threadIdx.x;
  for (int i = tid; i < 18 * 66; i += 256) {
    int r = i / 66, c = i % 66;
    int yy = y0 + r - 1, xx = x0 + c - 1;
    float v = 0.f;
    if (yy >= 0 && yy < HH && xx >= 0 && xx < WW2) v = Xc[yy * WW2 + xx];
    tile[r][c] = v;
  }
  __syncthreads();

  const int txx = tid & 15, tyy = tid >> 4;
  const int xx0 = txx * 4;
  float o0 = 0.f, o1 = 0.f, o2 = 0.f, o3 = 0.f;
#pragma unroll
  for (int ky = 0; ky < 3; ++ky) {
#pragma unroll
    for (int kx = 0; kx < 3; ++kx) {
      float wv = w[ky * 3 + kx];
      const float* tp = &tile[tyy + ky][xx0 + kx];
      o0 = fmaf(wv, tp[0], o0);
      o1 = fmaf(wv, tp[1], o1);
      o2 = fmaf(wv, tp[2], o2);
      o3 = fmaf(wv, tp[3], o3);
    }
  }
  float4 r4 = {o0, o1, o2, o3};
  *(float4*)(Yc + (size_t)(y0 + tyy) * WW2 + x0 + xx0) = r4;
}

// ---------------------------------------------------------------------------
// windowed channel attention: one block per (window, head).
// Reads q,k,v of its window from QKV ([b][C3][HW]); writes output IN-PLACE
// into the q-slice (safe: full window read into LDS before any write; blocks
// touch disjoint windows). Batch count set by grid size.
// ---------------------------------------------------------------------------
__global__ __launch_bounds__(256)
void attn_kernel(const float* __restrict__ QKV, const float* __restrict__ temp,
                 float* __restrict__ O /* == QKV q-slice, [b][C3][HW] */) {
  int gid = blockIdx.x;
  const int head = gid & 3;
  int win = gid >> 2;
  const int wn = win % WN; win /= WN;
  const int hn = win % HN;
  const int b  = win / HN;

  __shared__ __align__(16) float qT[64][52];
  __shared__ __align__(16) float kT[64][52];
  __shared__ __align__(16) float vs[48][64];
  __shared__ __align__(16) float att[48][52];
  __shared__ float inq[48], ink[48];

  const int tid = threadIdx.x;
  const size_t base = ((size_t)b * C3 + head * CP) * HW + (size_t)(hn * WS) * WW2 + wn * WS;

  for (int i = tid; i < 3 * CP * 64; i += 256) {
    int t = i / (CP * 64);
    int r = i % (CP * 64);
    int c = r >> 6;
    int p = r & 63;
    int p1 = p >> 3, p2 = p & 7;
    float v = QKV[base + (size_t)(t * DIM + c) * HW + p1 * WW2 + p2];
    if (t == 0)      qT[p][c] = v;
    else if (t == 1) kT[p][c] = v;
    else             vs[c][p] = v;
  }
  __syncthreads();

  // inverse norms (F.normalize: x / max(||x||, 1e-12))
  if (tid < 2 * CP) {
    int c = tid % CP;
    float s = 0.f;
    if (tid < CP) {
#pragma unroll 8
      for (int p = 0; p < 64; ++p) { float x = qT[p][c]; s = fmaf(x, x, s); }
      inq[c] = 1.0f / fmaxf(sqrtf(s), 1e-12f);
    } else {
#pragma unroll 8
      for (int p = 0; p < 64; ++p) { float x = kT[p][c]; s = fmaf(x, x, s); }
      ink[c] = 1.0f / fmaxf(sqrtf(s), 1e-12f);
    }
  }
  __syncthreads();

  const float tmpr = temp[head];
  for (int i = tid; i < CP * 12; i += 256) {
    int c  = i / 12;
    int e0 = (i % 12) * 4;
    float sx = 0.f, sy = 0.f, sz = 0.f, sw = 0.f;
#pragma unroll 8
    for (int p = 0; p < 64; ++p) {
      float qv = qT[p][c];
      float4 kv = *(const float4*)&kT[p][e0];
      sx = fmaf(qv, kv.x, sx);
      sy = fmaf(qv, kv.y, sy);
      sz = fmaf(qv, kv.z, sz);
      sw = fmaf(qv, kv.w, sw);
    }
    float qi = inq[c] * tmpr;
    float4 ki = *(const float4*)&ink[e0];
    float4 s4 = {sx * qi * ki.x, sy * qi * ki.y, sz * qi * ki.z, sw * qi * ki.w};
    *(float4*)&att[c][e0] = s4;
  }
  __syncthreads();

  // softmax over e (48) per row c
  if (tid < CP) {
    float m = -1e30f;
    for (int e = 0; e < CP; ++e) m = fmaxf(m, att[tid][e]);
    float sum = 0.f;
    for (int e = 0; e < CP; ++e) {
      float ev = __expf(att[tid][e] - m);
      att[tid][e] = ev;
      sum += ev;
    }
    float inv = 1.0f / sum;
    for (int e = 0; e < CP; ++e) att[tid][e] *= inv;
  }
  __syncthreads();

  // out[c][p] = sum_e att[c][e] * v[e][p]  -> q-slice position of this window
  for (int i = tid; i < CP * 64; i += 256) {
    int c = i >> 6, p = i & 63;
    float s = 0.f;
#pragma unroll 8
    for (int e = 0; e < CP; ++e) s = fmaf(att[c][e], vs[e][p], s);
    int p1 = p >> 3, p2 = p & 7;
    O[((size_t)b * C3 + head * CP + c) * HW + (size_t)(hn * WS + p1) * WW2 + wn * WS + p2] = s;
  }
}

// ---------------------------------------------------------------------------
extern "C" void kernel_launch(void* const* d_in, const int* in_sizes, int n_in,
                              void* d_out, int out_size, void* d_ws, size_t ws_size,
                              hipStream_t stream) {
  const float* x      = (const float*)d_in[0];
  const float* qkv_w  = (const float*)d_in[1];
  const float* dw_w   = (const float*)d_in[2];
  const float* proj_w = (const float*)d_in[3];
  const float* temp   = (const float*)d_in[4];
  float* out = (float*)d_out;

  const size_t full_need  = (size_t)NB * C3 * HW * sizeof(float);  // 302 MB
  const size_t batch_need = (size_t)C3 * HW * sizeof(float);       // 151 MB
  float* qkvd = (float*)d_ws;

  if (ws_size >= full_need) {
    // ---- full path: both batches at once; d_out doubles as conv tmp -------
    float* tmp = out;   // NB*DIM*HW fp32, dead until final proj overwrites it
    for (int t = 0; t < 3; ++t) {
      conv1x1_kernel<DIM><<<NB * (HW / 128) * (DIM / 64), 256, 0, stream>>>(
          qkv_w + (size_t)t * DIM * DIM, x, tmp,
          (size_t)DIM * HW, (size_t)DIM * HW, NB);
      dim3 g2(WW2 / 64, HH / 16, NB * DIM);
      dwconv_kernel<<<g2, 256, 0, stream>>>(
          dw_w + (size_t)t * DIM * 9, tmp, qkvd + (size_t)t * DIM * HW);
    }
    attn_kernel<<<NB * HN * WN * HEADS, 256, 0, stream>>>(qkvd, temp, qkvd);
    conv1x1_kernel<DIM><<<NB * (HW / 128) * (DIM / 64), 256, 0, stream>>>(
        proj_w, qkvd, out, (size_t)C3 * HW, (size_t)DIM * HW, NB);
  } else if (ws_size >= batch_need) {
    // ---- low-workspace fallback: one batch at a time ----------------------
    for (int b = 0; b < NB; ++b) {
      const float* xb = x + (size_t)b * DIM * HW;
      float* outb = out + (size_t)b * DIM * HW;   // tmp for this batch, then proj dst
      for (int t = 0; t < 3; ++t) {
        conv1x1_kernel<DIM><<<(HW / 128) * (DIM / 64), 256, 0, stream>>>(
            qkv_w + (size_t)t * DIM * DIM, xb, outb, 0, 0, 1);
        dim3 g2(WW2 / 64, HH / 16, DIM);
        dwconv_kernel<<<g2, 256, 0, stream>>>(
            dw_w + (size_t)t * DIM * 9, outb, qkvd + (size_t)t * DIM * HW);
      }
      attn_kernel<<<HN * WN * HEADS, 256, 0, stream>>>(qkvd, temp, qkvd);
      conv1x1_kernel<DIM><<<(HW / 128) * (DIM / 64), 256, 0, stream>>>(
          proj_w, qkvd, outb, 0, 0, 1);
    }
  } else {
    // diagnostic: ws too small even for per-batch path -> clean zero output
    hipMemsetAsync(d_out, 0, (size_t)out_size * sizeof(float), stream);
  }
}

// Round 7
// 801.404 us; speedup vs baseline: 1.4265x; 1.4265x over previous
//
#include <hip/hip_runtime.h>
#include <hip/hip_bf16.h>
#include <stdint.h>

#define HH 256
#define WW2 256
#define NB 2
#define DIM 192
#define HEADS 4
#define CP 48
#define WS 8
#define HN 32
#define WN 32
#define HW (HH*WW2)
#define C3 (3*DIM)

typedef __attribute__((ext_vector_type(8))) short bf16x8;
typedef __attribute__((ext_vector_type(4))) float f32x4;

// ---- fp32 -> (hi,lo) bf16 split, packed in one u32 (lo<<16 | hi) ----------
__device__ __forceinline__ uint32_t f2bf_bits(float x) {
  union { float f; uint32_t u; } a; a.f = x;
  uint32_t r = a.u + 0x7fffu + ((a.u >> 16) & 1u);   // RNE
  return r >> 16;
}
__device__ __forceinline__ float bf_bits2f(uint32_t b) {
  union { float f; uint32_t u; } a; a.u = b << 16; return a.f;
}
__device__ __forceinline__ uint32_t pack_split(float x) {
  uint32_t hi = f2bf_bits(x);
  float lo = x - bf_bits2f(hi);
  return (f2bf_bits(lo) << 16) | hi;
}

// ---------------------------------------------------------------------------
// 1x1 conv as GEMM via bf16x3-split MFMA (Markidis precision recovery).
// Y[b,o,n] = sum_c W[o,c] X[b,c,n], o tile 64, n tile 128, K-step 32.
// 4 waves: wave w covers n-cols [w*32, w*32+32); fragments 4(M) x 2(N).
// A_lds[m][k], B_lds[k][n] hold packed (hi|lo) u32; odd padding (37/131)
// keeps fragment reads <=2-way bank conflicts (free on CDNA4).
// bf16x3: acc += Ah*Bh + Ah*Bl + Al*Bh  (fp32 accum, ~fp32 precision;
// dropped Al*Bl term is ~2^-16 relative)
// ---------------------------------------------------------------------------
template<int COUT>
__global__ __launch_bounds__(256)
void conv1x1_mfma(const float* __restrict__ Wm, const float* __restrict__ X,
                  float* __restrict__ Y, size_t xbstride, size_t ybstride,
                  int nbat) {
  constexpr int OT = COUT / 64;        // 3
  constexpr int NT = HW / 128;         // 512
  const int TOTAL = nbat * NT * OT;
  int gid = blockIdx.x;
  int sw = (gid & 7) * (TOTAL >> 3) + (gid >> 3);   // XCD-chunked swizzle
  int o_t = sw % OT;
  int rem = sw / OT;
  int b   = rem % nbat;
  int n_t = rem / nbat;
  const int o0 = o_t * 64;
  const int n0 = n_t * 128;
  const float* Xb = X + (size_t)b * xbstride;
  float* Yb = Y + (size_t)b * ybstride;

  __shared__ uint32_t Als[64][37];     // [m][k] packed
  __shared__ uint32_t Bls[32][131];    // [k][n] packed

  const int tid  = threadIdx.x;
  const int lane = tid & 63;
  const int wid  = tid >> 6;
  const int l15  = lane & 15;
  const int kg   = lane >> 4;

  const f32x4 zero = {0.f, 0.f, 0.f, 0.f};
  f32x4 acc[4][2];
#pragma unroll
  for (int i = 0; i < 4; ++i)
#pragma unroll
    for (int j = 0; j < 2; ++j) acc[i][j] = zero;

  const int ka  = tid & 31, m0  = tid >> 5;   // A staging: k, m-base (0..7)
  const int nB  = tid & 127, kb0 = tid >> 7;  // B staging: n, k-base (0..1)

  for (int k0 = 0; k0 < DIM; k0 += 32) {
    __syncthreads();   // protect previous iter's fragment reads
    // stage A (64x32): W rows
#pragma unroll
    for (int j = 0; j < 8; ++j) {
      int m = m0 + j * 8;
      Als[m][ka] = pack_split(Wm[(size_t)(o0 + m) * DIM + k0 + ka]);
    }
    // stage B (32x128): coalesced X rows (128 consecutive floats)
#pragma unroll
    for (int j = 0; j < 16; ++j) {
      int k = kb0 + j * 2;
      Bls[k][nB] = pack_split(Xb[(size_t)(k0 + k) * HW + n0 + nB]);
    }
    __syncthreads();

    bf16x8 Ah[4], Alo[4], Bh[2], Blo[2];
#pragma unroll
    for (int fm = 0; fm < 4; ++fm) {
      uint32_t p[8];
      const uint32_t* ap = &Als[fm * 16 + l15][kg * 8];
#pragma unroll
      for (int i = 0; i < 8; ++i) p[i] = ap[i];
      union { uint32_t u[4]; bf16x8 v; } h, l;
#pragma unroll
      for (int r = 0; r < 4; ++r) {
        h.u[r] = (p[2*r+1] << 16) | (p[2*r] & 0xffffu);
        l.u[r] = (p[2*r+1] & 0xffff0000u) | (p[2*r] >> 16);
      }
      Ah[fm] = h.v; Alo[fm] = l.v;
    }
#pragma unroll
    for (int fn = 0; fn < 2; ++fn) {
      const int ncol = wid * 32 + fn * 16 + l15;
      uint32_t p[8];
#pragma unroll
      for (int i = 0; i < 8; ++i) p[i] = Bls[kg * 8 + i][ncol];
      union { uint32_t u[4]; bf16x8 v; } h, l;
#pragma unroll
      for (int r = 0; r < 4; ++r) {
        h.u[r] = (p[2*r+1] << 16) | (p[2*r] & 0xffffu);
        l.u[r] = (p[2*r+1] & 0xffff0000u) | (p[2*r] >> 16);
      }
      Bh[fn] = h.v; Blo[fn] = l.v;
    }
#pragma unroll
    for (int fm = 0; fm < 4; ++fm)
#pragma unroll
      for (int fn = 0; fn < 2; ++fn) {
        acc[fm][fn] = __builtin_amdgcn_mfma_f32_16x16x32_bf16(Ah[fm],  Bh[fn],  acc[fm][fn], 0, 0, 0);
        acc[fm][fn] = __builtin_amdgcn_mfma_f32_16x16x32_bf16(Ah[fm],  Blo[fn], acc[fm][fn], 0, 0, 0);
        acc[fm][fn] = __builtin_amdgcn_mfma_f32_16x16x32_bf16(Alo[fm], Bh[fn],  acc[fm][fn], 0, 0, 0);
      }
  }

  // epilogue: D layout col = lane&15, row = (lane>>4)*4 + reg  [m89-verified]
  const int rb = (lane >> 4) * 4;
#pragma unroll
  for (int fm = 0; fm < 4; ++fm)
#pragma unroll
    for (int fn = 0; fn < 2; ++fn) {
      const int n = n0 + wid * 32 + fn * 16 + l15;
#pragma unroll
      for (int r = 0; r < 4; ++r) {
        const int o = o0 + fm * 16 + rb + r;
        Yb[(size_t)o * HW + n] = acc[fm][fn][r];
      }
    }
}

// ---------------------------------------------------------------------------
// depthwise 3x3, SAME padding, one 192-channel chunk (validated round 5)
// ---------------------------------------------------------------------------
__global__ __launch_bounds__(256)
void dwconv_kernel(const float* __restrict__ Wd, const float* __restrict__ X,
                   float* __restrict__ Y) {
  const int bc = blockIdx.z;          // b*DIM + ch
  const int ch = bc % DIM;
  const int b  = bc / DIM;
  const int y0 = blockIdx.y * 16;
  const int x0 = blockIdx.x * 64;
  const float* Xc = X + (size_t)bc * HW;
  float* Yc = Y + ((size_t)b * C3 + ch) * HW;

  float w[9];
#pragma unroll
  for (int i = 0; i < 9; ++i) w[i] = Wd[ch * 9 + i];

  __shared__ __align__(16) float tile[18][66];
  const int tid = threadIdx.x;
  for (int i = tid; i < 18 * 66; i += 256) {
    int r = i / 66, c = i % 66;
    int yy = y0 + r - 1, xx = x0 + c - 1;
    float v = 0.f;
    if (yy >= 0 && yy < HH && xx >= 0 && xx < WW2) v = Xc[yy * WW2 + xx];
    tile[r][c] = v;
  }
  __syncthreads();

  const int txx = tid & 15, tyy = tid >> 4;
  const int xx0 = txx * 4;
  float o0 = 0.f, o1 = 0.f, o2 = 0.f, o3 = 0.f;
#pragma unroll
  for (int ky = 0; ky < 3; ++ky) {
#pragma unroll
    for (int kx = 0; kx < 3; ++kx) {
      float wv = w[ky * 3 + kx];
      const float* tp = &tile[tyy + ky][xx0 + kx];
      o0 = fmaf(wv, tp[0], o0);
      o1 = fmaf(wv, tp[1], o1);
      o2 = fmaf(wv, tp[2], o2);
      o3 = fmaf(wv, tp[3], o3);
    }
  }
  float4 r4 = {o0, o1, o2, o3};
  *(float4*)(Yc + (size_t)(y0 + tyy) * WW2 + x0 + xx0) = r4;
}

// ---------------------------------------------------------------------------
// windowed channel attention, wave-parallel (fp32 numerics unchanged vs ref).
//  - float2 global loads
//  - 2-lane shuffle norms (192 threads)
//  - QK^T: 3x3 register tile per thread (256 threads, 16x16 grid)
//  - softmax: 48 rows x 4 lanes, shfl_xor reduce; 1/sum deferred to PV store
//  - PV: 3(c) x 4(p) register tile, float4 vs reads
// Output written in-place into the q-slice of QKV (disjoint windows; all
// reads complete + barrier before first write).
// ---------------------------------------------------------------------------
__global__ __launch_bounds__(256)
void attn_kernel(const float* __restrict__ QKV, const float* __restrict__ temp,
                 float* __restrict__ O /* == QKV q-slice, [b][C3][HW] */) {
  int gid = blockIdx.x;
  const int head = gid & 3;
  int win = gid >> 2;
  const int wn = win % WN; win /= WN;
  const int hn = win % HN;
  const int b  = win / HN;

  __shared__ float qT[64][49];
  __shared__ float kT[64][49];
  __shared__ __align__(16) float vs[48][68];
  __shared__ float att[48][49];
  __shared__ float inq[48], ink[48], isum[48];

  const int tid = threadIdx.x;
  const size_t base = ((size_t)b * C3 + head * CP) * HW
                    + (size_t)(hn * WS) * WW2 + wn * WS;

  // ---- load q,k,v (float2: 3*48*8*4 = 4608 jobs, 18 per thread) ----------
  for (int i = tid; i < 4608; i += 256) {
    int t  = i / 1536;
    int r  = i - t * 1536;
    int c  = r >> 5;          // 0..47
    int rr = (r >> 2) & 7;    // window row
    int l2 = r & 3;           // float2 index
    float2 v = *(const float2*)(QKV + base + (size_t)(t * DIM + c) * HW
                                + (size_t)rr * WW2 + l2 * 2);
    int p = rr * 8 + l2 * 2;
    if (t == 0)      { qT[p][c] = v.x; qT[p + 1][c] = v.y; }
    else if (t == 1) { kT[p][c] = v.x; kT[p + 1][c] = v.y; }
    else             { vs[c][p] = v.x; vs[c][p + 1] = v.y; }
  }
  __syncthreads();

  // ---- inverse norms: 2 lanes per (tensor, c) ----------------------------
  if (tid < 192) {
    int pair = tid >> 1, half = tid & 1;
    int c = pair % 48, tq = pair / 48;
    int p0 = half * 32;
    float s = 0.f;
    if (tq == 0) {
#pragma unroll 8
      for (int p = p0; p < p0 + 32; ++p) { float x = qT[p][c]; s = fmaf(x, x, s); }
    } else {
#pragma unroll 8
      for (int p = p0; p < p0 + 32; ++p) { float x = kT[p][c]; s = fmaf(x, x, s); }
    }
    s += __shfl_xor(s, 1);
    if (half == 0) {
      float inv = 1.0f / fmaxf(sqrtf(s), 1e-12f);
      if (tq == 0) inq[c] = inv; else ink[c] = inv;
    }
  }
  __syncthreads();

  const float tmpr = temp[head];

  // ---- QK^T: 3x3 tile per thread -----------------------------------------
  {
    const int ct = tid & 15, et = tid >> 4;
    const int c0 = ct * 3, e0 = et * 3;
    float a00=0,a01=0,a02=0,a10=0,a11=0,a12=0,a20=0,a21=0,a22=0;
#pragma unroll 4
    for (int p = 0; p < 64; ++p) {
      float q0 = qT[p][c0], q1 = qT[p][c0+1], q2 = qT[p][c0+2];
      float k0 = kT[p][e0], k1 = kT[p][e0+1], k2 = kT[p][e0+2];
      a00 = fmaf(q0,k0,a00); a01 = fmaf(q0,k1,a01); a02 = fmaf(q0,k2,a02);
      a10 = fmaf(q1,k0,a10); a11 = fmaf(q1,k1,a11); a12 = fmaf(q1,k2,a12);
      a20 = fmaf(q2,k0,a20); a21 = fmaf(q2,k1,a21); a22 = fmaf(q2,k2,a22);
    }
    float qi0 = inq[c0] * tmpr, qi1 = inq[c0+1] * tmpr, qi2 = inq[c0+2] * tmpr;
    float ki0 = ink[e0], ki1 = ink[e0+1], ki2 = ink[e0+2];
    att[c0  ][e0] = a00*qi0*ki0; att[c0  ][e0+1] = a01*qi0*ki1; att[c0  ][e0+2] = a02*qi0*ki2;
    att[c0+1][e0] = a10*qi1*ki0; att[c0+1][e0+1] = a11*qi1*ki1; att[c0+1][e0+2] = a12*qi1*ki2;
    att[c0+2][e0] = a20*qi2*ki0; att[c0+2][e0+1] = a21*qi2*ki1; att[c0+2][e0+2] = a22*qi2*ki2;
  }
  __syncthreads();

  // ---- softmax: 48 rows x 4 lanes; store exp, defer 1/sum ----------------
  if (tid < 192) {
    int c = tid >> 2, l = tid & 3;
    int e0 = l * 12;
    float v0[12];
    float m = -1e30f;
#pragma unroll
    for (int j = 0; j < 12; ++j) { v0[j] = att[c][e0 + j]; m = fmaxf(m, v0[j]); }
    m = fmaxf(m, __shfl_xor(m, 1));
    m = fmaxf(m, __shfl_xor(m, 2));
    float s = 0.f;
#pragma unroll
    for (int j = 0; j < 12; ++j) {
      float ev = __expf(v0[j] - m);
      att[c][e0 + j] = ev;
      s += ev;
    }
    s += __shfl_xor(s, 1);
    s += __shfl_xor(s, 2);
    if (l == 0) isum[c] = 1.0f / s;
  }
  __syncthreads();

  // ---- PV: 3(c) x 4(p) tile per thread; scale by isum at store -----------
  {
    const int ct = tid & 15, pt = tid >> 4;
    const int c0 = ct * 3, p0 = pt * 4;
    float o00=0,o01=0,o02=0,o03=0,o10=0,o11=0,o12=0,o13=0,o20=0,o21=0,o22=0,o23=0;
#pragma unroll 4
    for (int e = 0; e < 48; ++e) {
      float a0 = att[c0][e], a1 = att[c0+1][e], a2 = att[c0+2][e];
      float4 v4 = *(const float4*)&vs[e][p0];
      o00 = fmaf(a0,v4.x,o00); o01 = fmaf(a0,v4.y,o01); o02 = fmaf(a0,v4.z,o02); o03 = fmaf(a0,v4.w,o03);
      o10 = fmaf(a1,v4.x,o10); o11 = fmaf(a1,v4.y,o11); o12 = fmaf(a1,v4.z,o12); o13 = fmaf(a1,v4.w,o13);
      o20 = fmaf(a2,v4.x,o20); o21 = fmaf(a2,v4.y,o21); o22 = fmaf(a2,v4.z,o22); o23 = fmaf(a2,v4.w,o23);
    }
    const int p1 = pt >> 1, p2o = (pt & 1) * 4;
    float s0 = isum[c0], s1 = isum[c0+1], s2 = isum[c0+2];
    float4 w0 = {o00*s0, o01*s0, o02*s0, o03*s0};
    float4 w1 = {o10*s1, o11*s1, o12*s1, o13*s1};
    float4 w2 = {o20*s2, o21*s2, o22*s2, o23*s2};
    *(float4*)(O + base + (size_t)(c0    ) * HW + (size_t)p1 * WW2 + p2o) = w0;
    *(float4*)(O + base + (size_t)(c0 + 1) * HW + (size_t)p1 * WW2 + p2o) = w1;
    *(float4*)(O + base + (size_t)(c0 + 2) * HW + (size_t)p1 * WW2 + p2o) = w2;
  }
}

// ---------------------------------------------------------------------------
extern "C" void kernel_launch(void* const* d_in, const int* in_sizes, int n_in,
                              void* d_out, int out_size, void* d_ws, size_t ws_size,
                              hipStream_t stream) {
  const float* x      = (const float*)d_in[0];
  const float* qkv_w  = (const float*)d_in[1];
  const float* dw_w   = (const float*)d_in[2];
  const float* proj_w = (const float*)d_in[3];
  const float* temp   = (const float*)d_in[4];
  float* out = (float*)d_out;

  const size_t full_need  = (size_t)NB * C3 * HW * sizeof(float);  // 302 MB
  const size_t batch_need = (size_t)C3 * HW * sizeof(float);       // 151 MB
  float* qkvd = (float*)d_ws;

  if (ws_size >= full_need) {
    // ---- full path: both batches at once; d_out doubles as conv tmp ------
    float* tmp = out;   // NB*DIM*HW fp32, dead until final proj overwrites it
    for (int t = 0; t < 3; ++t) {
      conv1x1_mfma<DIM><<<NB * (HW / 128) * (DIM / 64), 256, 0, stream>>>(
          qkv_w + (size_t)t * DIM * DIM, x, tmp,
          (size_t)DIM * HW, (size_t)DIM * HW, NB);
      dim3 g2(WW2 / 64, HH / 16, NB * DIM);
      dwconv_kernel<<<g2, 256, 0, stream>>>(
          dw_w + (size_t)t * DIM * 9, tmp, qkvd + (size_t)t * DIM * HW);
    }
    attn_kernel<<<NB * HN * WN * HEADS, 256, 0, stream>>>(qkvd, temp, qkvd);
    conv1x1_mfma<DIM><<<NB * (HW / 128) * (DIM / 64), 256, 0, stream>>>(
        proj_w, qkvd, out, (size_t)C3 * HW, (size_t)DIM * HW, NB);
  } else if (ws_size >= batch_need) {
    // ---- low-workspace fallback: one batch at a time ---------------------
    for (int b = 0; b < NB; ++b) {
      const float* xb = x + (size_t)b * DIM * HW;
      float* outb = out + (size_t)b * DIM * HW;
      for (int t = 0; t < 3; ++t) {
        conv1x1_mfma<DIM><<<(HW / 128) * (DIM / 64), 256, 0, stream>>>(
            qkv_w + (size_t)t * DIM * DIM, xb, outb, 0, 0, 1);
        dim3 g2(WW2 / 64, HH / 16, DIM);
        dwconv_kernel<<<g2, 256, 0, stream>>>(
            dw_w + (size_t)t * DIM * 9, outb, qkvd + (size_t)t * DIM * HW);
      }
      attn_kernel<<<HN * WN * HEADS, 256, 0, stream>>>(qkvd, temp, qkvd);
      conv1x1_mfma<DIM><<<(HW / 128) * (DIM / 64), 256, 0, stream>>>(
          proj_w, qkvd, outb, 0, 0, 1);
    }
  } else {
    hipMemsetAsync(d_out, 0, (size_t)out_size * sizeof(float), stream);
  }
}